// Round 1
// baseline (64.457 us; speedup 1.0000x reference)
//
#include <hip/hip_runtime.h>

#define B_SZ 2048
#define F_SZ 24
#define E_SZ 128
#define P_SZ 276   // F*(F-1)/2
#define BT   64    // batch rows per block
#define NB   (B_SZ / BT)  // 32 batch blocks

typedef __bf16 bf16x8 __attribute__((ext_vector_type(8)));
typedef float  f32x4  __attribute__((ext_vector_type(4)));

__device__ inline unsigned short f2b(float f) {
    __bf16 h = (__bf16)f;                      // RNE convert; compiler pairs into cvt_pk
    return __builtin_bit_cast(unsigned short, h);
}

__global__ __launch_bounds__(256) void opn_pairwise_kernel(
    const float* __restrict__ x,      // [B, F, E]
    const float* __restrict__ kern,   // [E(d), P, E(e)]
    float* __restrict__ out)          // [B, P]
{
    // LDS: bf16 tiles, XOR-swizzled at 8-element (16B) granularity
    __shared__ short sA[BT * E_SZ];     // Xp tile  (64 x 128)  16 KB
    __shared__ short sB[E_SZ * E_SZ];   // K_p tile (128 x 128) 32 KB
    __shared__ float red[4][BT];        // cross-wave d-reduction, 1 KB

    const int tid = threadIdx.x;
    const int p  = blockIdx.x / NB;     // p-major: 32 consecutive blocks share K_p
    const int bb = blockIdx.x % NB;
    const int b0 = bb * BT;

    // p -> (fp, fq) for triu_indices(F, k=1), row-major pair order
    int fp = 0, rem = p;
    while (rem >= F_SZ - 1 - fp) { rem -= F_SZ - 1 - fp; ++fp; }
    const int fq = fp + 1 + rem;

    // ---- stage Xp: 64 rows x 128, fp32 -> bf16, swizzled ----
#pragma unroll
    for (int k = 0; k < 8; ++k) {
        int i = tid + k * 256;          // 0..2047 float4 index
        int r = i >> 5, e4 = i & 31;
        float4 v = *(const float4*)(x + ((size_t)(b0 + r) * F_SZ + fp) * E_SZ + e4 * 4);
        int e  = e4 * 4;
        int es = e ^ ((r & 7) << 3);
        ushort4 h;
        h.x = f2b(v.x); h.y = f2b(v.y); h.z = f2b(v.z); h.w = f2b(v.w);
        *(ushort4*)&sA[r * E_SZ + es] = h;
    }
    // ---- stage K_p: 128 rows(d) x 128(e), row stride P*E in global ----
#pragma unroll
    for (int k = 0; k < 16; ++k) {
        int i = tid + k * 256;          // 0..4095 float4 index
        int d = i >> 5, e4 = i & 31;
        float4 v = *(const float4*)(kern + ((size_t)d * P_SZ + p) * E_SZ + e4 * 4);
        int e  = e4 * 4;
        int es = e ^ ((d & 7) << 3);
        ushort4 h;
        h.x = f2b(v.x); h.y = f2b(v.y); h.z = f2b(v.z); h.w = f2b(v.w);
        *(ushort4*)&sB[d * E_SZ + es] = h;
    }
    __syncthreads();

    const int w = tid >> 6, lane = tid & 63;
    const int c = lane & 15, g = lane >> 4;

    // ---- MFMA: T[64 x 128] = Xp(64xE) . K_p(d,e)^T ; wave w owns n-tiles {2w,2w+1}
    f32x4 acc[4][2];
#pragma unroll
    for (int mt = 0; mt < 4; ++mt)
#pragma unroll
        for (int nt = 0; nt < 2; ++nt)
            acc[mt][nt] = (f32x4){0.f, 0.f, 0.f, 0.f};

#pragma unroll
    for (int kk = 0; kk < 4; ++kk) {
        const int e0 = kk * 32 + g * 8;
        bf16x8 afr[4], bfr[2];
#pragma unroll
        for (int mt = 0; mt < 4; ++mt) {
            int row = mt * 16 + c;      // A fragment: m = lane&15
            afr[mt] = *(const bf16x8*)&sA[row * E_SZ + (e0 ^ ((row & 7) << 3))];
        }
#pragma unroll
        for (int nt = 0; nt < 2; ++nt) {
            int d = (w * 2 + nt) * 16 + c;  // B fragment: n(col=d) = lane&15, k = e
            bfr[nt] = *(const bf16x8*)&sB[d * E_SZ + (e0 ^ ((d & 7) << 3))];
        }
#pragma unroll
        for (int mt = 0; mt < 4; ++mt)
#pragma unroll
            for (int nt = 0; nt < 2; ++nt)
                acc[mt][nt] = __builtin_amdgcn_mfma_f32_16x16x32_bf16(
                    afr[mt], bfr[nt], acc[mt][nt], 0, 0, 0);
    }

    // ---- epilogue: s[b] = sum_d T[b,d] * Xq[b,d], this wave's 32 d's ----
    // D layout: row = g*4 + j (batch within tile), col = c (d within tile)
    float s[4][4];
#pragma unroll
    for (int mt = 0; mt < 4; ++mt)
#pragma unroll
        for (int j = 0; j < 4; ++j) s[mt][j] = 0.f;

#pragma unroll
    for (int nt = 0; nt < 2; ++nt) {
        const int d = (w * 2 + nt) * 16 + c;
#pragma unroll
        for (int mt = 0; mt < 4; ++mt) {
#pragma unroll
            for (int j = 0; j < 4; ++j) {
                int row = mt * 16 + g * 4 + j;
                float xq = x[((size_t)(b0 + row) * F_SZ + fq) * E_SZ + d];
                s[mt][j] += acc[mt][nt][j] * xq;
            }
        }
    }
    // reduce over the 16 column lanes (d within n-tile)
#pragma unroll
    for (int mt = 0; mt < 4; ++mt)
#pragma unroll
        for (int j = 0; j < 4; ++j) {
            float v = s[mt][j];
            v += __shfl_xor(v, 1);
            v += __shfl_xor(v, 2);
            v += __shfl_xor(v, 4);
            v += __shfl_xor(v, 8);
            s[mt][j] = v;
        }
    if (c == 0) {
#pragma unroll
        for (int mt = 0; mt < 4; ++mt)
#pragma unroll
            for (int j = 0; j < 4; ++j)
                red[w][mt * 16 + g * 4 + j] = s[mt][j];
    }
    __syncthreads();

    // cross-wave reduction over the 4 d-ranges, then store out[b, p]
    if (tid < BT) {
        float r = red[0][tid] + red[1][tid] + red[2][tid] + red[3][tid];
        out[(size_t)(b0 + tid) * P_SZ + p] = r;
    }
}

extern "C" void kernel_launch(void* const* d_in, const int* in_sizes, int n_in,
                              void* d_out, int out_size, void* d_ws, size_t ws_size,
                              hipStream_t stream) {
    const float* x    = (const float*)d_in[0];   // [2048, 24, 128] f32
    const float* kern = (const float*)d_in[1];   // [128, 276, 128] f32
    float* out = (float*)d_out;                  // [2048, 276] f32
    dim3 grid(P_SZ * NB);                        // 8832 blocks, p-major
    opn_pairwise_kernel<<<grid, 256, 0, stream>>>(x, kern, out);
}